// Round 9
// baseline (59.814 us; speedup 1.0000x reference)
//
#include <hip/hip_runtime.h>
#include <hip/hip_bf16.h>

typedef float  f32x4  __attribute__((ext_vector_type(4)));
typedef short  short8 __attribute__((ext_vector_type(8)));

#define NKT 25
#define BM  128
#define AB  8192              // one A buffer: [4][128][8] bf16
#define BB  8192              // one B buffer: [4][128][8] bf16
#define BOFF (3 * AB)         // B region starts after 3 A buffers
#define POOLB (3 * AB + 4 * BB)   // 57344 B

static __device__ __forceinline__ unsigned short f2bf(float f) {
    unsigned int u = __float_as_uint(f);
    unsigned int r = (u + 0x7fffu + ((u >> 16) & 1u)) >> 16;   // RNE
    return (unsigned short)r;
}
static __device__ __forceinline__ float bf2f(unsigned short h) {
    return __uint_as_float(((unsigned int)h) << 16);
}
static __device__ __forceinline__ uint2 pack4(f32x4 v) {
    __hip_bfloat162 p0 = __float22bfloat162_rn(make_float2(v[0], v[1]));
    __hip_bfloat162 p1 = __float22bfloat162_rn(make_float2(v[2], v[3]));
    uint2 r;
    r.x = *reinterpret_cast<unsigned int*>(&p0);
    r.y = *reinterpret_cast<unsigned int*>(&p1);
    return r;
}

// W_eff = fc1_w o ConvMatrix, layout [kt][k2][128 cols][8] bf16:
// idx = kt*4096 + (kk>>3)*1024 + o*8 + (kk&7), p = kt*32+kk. Zero past 783.
__global__ __launch_bounds__(256) void weff_prep(
    const float* __restrict__ fc1_w,    // [128][676]
    const float* __restrict__ conv_w,   // [3][3]
    unsigned short* __restrict__ weff4) // [25][4][128][8] bf16
{
    int idx = blockIdx.x * 256 + threadIdx.x;   // o*800 + p
    if (idx >= 128 * 800) return;
    int o = idx / 800, p = idx - o * 800;
    float s = 0.f;
    if (p < 784) {
        int y = p / 28, xx = p - y * 28;
        #pragma unroll
        for (int dr = 0; dr < 3; ++dr) {
            int r = y - dr;
            if (r < 0 || r > 25) continue;
            #pragma unroll
            for (int dc = 0; dc < 3; ++dc) {
                int c = xx - dc;
                if (c < 0 || c > 25) continue;
                s += fc1_w[o * 676 + r * 26 + c] * conv_w[dr * 3 + dc];
            }
        }
    }
    int kt = p >> 5, kk = p & 31;
    weff4[kt * 4096 + (kk >> 3) * 1024 + o * 8 + (kk & 7)] = f2bf(s);
}

// Fused: H = relu(X @ Weff^T + b1); out = H @ fc2^T + b2
// LDS-traffic-minimized pipeline: A reg-staged f32->bf16 (2-step flight,
// 3 LDS bufs), B via linear global_load_lds (3-step flight, 4 bufs).
// k-major LDS layouts -> all frag reads 256B-dense, conflict-free.
// ONE s_barrier per K-step, counted vmcnt(6). 8 waves: 4 row x 2 col.
__global__ __launch_bounds__(512, 4) void fused_fwd(
    const float* __restrict__ x,              // [B][784]
    const unsigned short* __restrict__ weff4, // [25][4][128][8] bf16
    const float* __restrict__ fc1_b,          // [128]
    const float* __restrict__ fc2_w,          // [10][128]
    const float* __restrict__ fc2_b,          // [10]
    float* __restrict__ out,                  // [B][10]
    int B)
{
    __shared__ __align__(16) char pool[POOLB];   // 56 KB; Hs overlays after
    __shared__ float fc2w_s[1280];
    __shared__ float fc2b_s[16];

    const int tid  = threadIdx.x;
    const int lane = tid & 63;
    const int wid  = tid >> 6;                // 0..7
    const int wr   = wid >> 1;                // 0..3: 32-row band
    const int wc   = wid & 1;                 // 0..1: 64-col half
    const int r16  = lane & 15;
    const int kc   = lane >> 4;               // 0..3 (8-bf16 k-chunk)
    const int m0   = blockIdx.x * BM;

    for (int i = tid; i < 1280; i += 512) fc2w_s[i] = fc2_w[i];
    if (tid < 10) fc2b_s[tid] = fc2_b[tid];
    asm volatile("s_waitcnt vmcnt(0)" ::: "memory");   // clean vmcnt FIFO

    // ---- A staging geometry: thread t -> rows {sr, sr+64}, k-granule g
    const int sr   = tid >> 3;                // 0..63
    const int g    = tid & 7;                 // 4-f32 granule in 32-k step
    const int k2w  = g >> 1, half = g & 1;
    int row0 = m0 + sr;      if (row0 >= B) row0 = B - 1;
    int row1 = m0 + sr + 64; if (row1 >= B) row1 = B - 1;
    const float* xr0 = x + (size_t)row0 * 784;
    const float* xr1 = x + (size_t)row1 * 784;
    const int awb = k2w * 2048 + sr * 16 + half * 8;   // byte off in A buf

    f32x4 av[3][2];                            // [set][row-half]

#define LD_A(s_, kt_) do {                                                    \
        int k_ = (kt_) * 32 + g * 4; if (k_ > 780) k_ = 0;                    \
        av[s_][0] = *reinterpret_cast<const f32x4*>(xr0 + k_);                \
        av[s_][1] = *reinterpret_cast<const f32x4*>(xr1 + k_);                \
    } while (0)

#define WR_A(s_, bi_) do {                                                    \
        uint2 q0_ = pack4(av[s_][0]);                                         \
        uint2 q1_ = pack4(av[s_][1]);                                         \
        char* ba_ = pool + (bi_) * AB + awb;                                  \
        *reinterpret_cast<uint2*>(ba_)        = q0_;                          \
        *reinterpret_cast<uint2*>(ba_ + 1024) = q1_;                          \
    } while (0)

#define GL_B(bi_, kt_) __builtin_amdgcn_global_load_lds(                      \
        (const __attribute__((address_space(1))) void*)                      \
            (weff4 + (size_t)(kt_) * 4096 + tid * 8),                         \
        (__attribute__((address_space(3))) void*)                            \
            (pool + BOFF + (bi_) * BB + tid * 16), 16, 0, 0)

    // ---- frag read offsets (k-major, conflict-free)
    const int aoff = kc * 2048 + (wr * 32 + r16) * 16;       // m=1: +256
    const int boff = BOFF + kc * 2048 + (wc * 64 + r16) * 16; // j: +256

    f32x4 acc[2][4];
    #pragma unroll
    for (int m = 0; m < 2; ++m)
        #pragma unroll
        for (int j = 0; j < 4; ++j) acc[m][j] = (f32x4)(0.f);

    // ---- prologue: FIFO = [A0 x2, B0, B1, B2, A1 x2, A2 x2]
    LD_A(0, 0);
    GL_B(0, 0); GL_B(1, 1); GL_B(2, 2);
    LD_A(1, 1); LD_A(2, 2);
    WR_A(0, 0);                                // compiler auto-waits A0

    #pragma unroll
    for (int i = 0; i < NKT; ++i) {
        asm volatile("s_waitcnt vmcnt(6) lgkmcnt(0)" ::: "memory");
        __builtin_amdgcn_s_barrier();
        __builtin_amdgcn_sched_barrier(0);

        const char* pa = pool + (i % 3) * AB;
        const char* pb = pool + (i % 4) * BB;   // relative to BOFF via boff
        short8 a0 = *reinterpret_cast<const short8*>(pa + aoff);
        short8 a1 = *reinterpret_cast<const short8*>(pa + aoff + 256);
        short8 b0 = *reinterpret_cast<const short8*>(pb + boff);
        short8 b1 = *reinterpret_cast<const short8*>(pb + boff + 256);
        short8 b2 = *reinterpret_cast<const short8*>(pb + boff + 512);
        short8 b3 = *reinterpret_cast<const short8*>(pb + boff + 768);

        const int kn = (i + 3 <= 24) ? (i + 3) : 24;
        LD_A((i + 3) % 3, kn);                 // issue early (T14)
        GL_B((i + 3) % 4, kn);
        WR_A((i + 1) % 3, (i + 1) % 3);        // write-late into next buf

        acc[0][0] = __builtin_amdgcn_mfma_f32_16x16x32_bf16(a0, b0, acc[0][0], 0, 0, 0);
        acc[0][1] = __builtin_amdgcn_mfma_f32_16x16x32_bf16(a0, b1, acc[0][1], 0, 0, 0);
        acc[0][2] = __builtin_amdgcn_mfma_f32_16x16x32_bf16(a0, b2, acc[0][2], 0, 0, 0);
        acc[0][3] = __builtin_amdgcn_mfma_f32_16x16x32_bf16(a0, b3, acc[0][3], 0, 0, 0);
        acc[1][0] = __builtin_amdgcn_mfma_f32_16x16x32_bf16(a1, b0, acc[1][0], 0, 0, 0);
        acc[1][1] = __builtin_amdgcn_mfma_f32_16x16x32_bf16(a1, b1, acc[1][1], 0, 0, 0);
        acc[1][2] = __builtin_amdgcn_mfma_f32_16x16x32_bf16(a1, b2, acc[1][2], 0, 0, 0);
        acc[1][3] = __builtin_amdgcn_mfma_f32_16x16x32_bf16(a1, b3, acc[1][3], 0, 0, 0);
    }
#undef LD_A
#undef WR_A
#undef GL_B

    // drain all in-flight loads/writes before overlaying the pool
    asm volatile("s_waitcnt vmcnt(0) lgkmcnt(0)" ::: "memory");
    __builtin_amdgcn_s_barrier();
    __builtin_amdgcn_sched_barrier(0);

    // ---- epilogue: bias + ReLU -> Hs (bf16), overlays pool ----
    unsigned short (*Hs)[136] = (unsigned short (*)[136])pool;
    #pragma unroll
    for (int m = 0; m < 2; ++m) {
        #pragma unroll
        for (int j = 0; j < 4; ++j) {
            int ncol = wc * 64 + j * 16 + r16;
            float bias = fc1_b[ncol];
            #pragma unroll
            for (int r = 0; r < 4; ++r) {
                int mrow = wr * 32 + m * 16 + kc * 4 + r;
                float h = acc[m][j][r] + bias;
                Hs[mrow][ncol] = f2bf(h > 0.f ? h : 0.f);
            }
        }
    }
    __syncthreads();

    // ---- stage 2: out[128][10] = Hs @ fc2^T + b2 ----
    #pragma unroll
    for (int it = 0; it < 3; ++it) {
        int idx = it * 512 + tid;              // 0..1535, valid < 1280
        if (idx < BM * 10) {
            int row = idx / 10, j = idx - row * 10;
            if ((m0 + row) < B) {
                float sum = fc2b_s[j];
                const float* wrow = &fc2w_s[j * 128];
                #pragma unroll
                for (int n8 = 0; n8 < 16; ++n8) {
                    short8 h = *reinterpret_cast<const short8*>(&Hs[row][n8 * 8]);
                    #pragma unroll
                    for (int k2 = 0; k2 < 8; ++k2)
                        sum += bf2f(((unsigned short*)&h)[k2]) * wrow[n8 * 8 + k2];
                }
                out[(size_t)(m0 + row) * 10 + j] = sum;
            }
        }
    }
}

extern "C" void kernel_launch(void* const* d_in, const int* in_sizes, int n_in,
                              void* d_out, int out_size, void* d_ws, size_t ws_size,
                              hipStream_t stream) {
    const float* x      = (const float*)d_in[0];
    const float* conv_w = (const float*)d_in[1];
    const float* fc1_w  = (const float*)d_in[2];
    const float* fc1_b  = (const float*)d_in[3];
    const float* fc2_w  = (const float*)d_in[4];
    const float* fc2_b  = (const float*)d_in[5];
    float* out = (float*)d_out;
    unsigned short* weff4 = (unsigned short*)d_ws;   // 25*4096*2 = 204800 B

    int B = in_sizes[0] / 784;

    weff_prep<<<(128 * 800 + 255) / 256, 256, 0, stream>>>(fc1_w, conv_w, weff4);

    int nblk = (B + BM - 1) / BM;
    fused_fwd<<<nblk, 512, 0, stream>>>(x, weff4, fc1_b, fc2_w, fc2_b, out, B);
}

// Round 10
// 58.952 us; speedup vs baseline: 1.0146x; 1.0146x over previous
//
#include <hip/hip_runtime.h>
#include <hip/hip_bf16.h>

typedef float  f32x4  __attribute__((ext_vector_type(4)));
typedef short  short8 __attribute__((ext_vector_type(8)));

#define NKT   25
#define BM    64
#define AB    4096            // A buf: [4][64][8] bf16
#define BB    8192            // B buf: [4][128][8] bf16
#define BOFFS (3 * AB)        // 12288
#define POOLB (3 * AB + 3 * BB)   // 36864 -> 4 blocks/CU

static __device__ __forceinline__ unsigned short f2bf(float f) {
    unsigned int u = __float_as_uint(f);
    unsigned int r = (u + 0x7fffu + ((u >> 16) & 1u)) >> 16;   // RNE
    return (unsigned short)r;
}
static __device__ __forceinline__ float bf2f(unsigned short h) {
    return __uint_as_float(((unsigned int)h) << 16);
}
static __device__ __forceinline__ uint2 pack4(f32x4 v) {
    __hip_bfloat162 p0 = __float22bfloat162_rn(make_float2(v[0], v[1]));
    __hip_bfloat162 p1 = __float22bfloat162_rn(make_float2(v[2], v[3]));
    uint2 r;
    r.x = *reinterpret_cast<unsigned int*>(&p0);
    r.y = *reinterpret_cast<unsigned int*>(&p1);
    return r;
}

// W_eff = fc1_w o ConvMatrix, layout [kt][k2][128 cols][8] bf16 at ws[0..102399];
// fc2 weights converted to bf16 at ws[102400..103679].
__global__ __launch_bounds__(256) void weff_prep(
    const float* __restrict__ fc1_w,    // [128][676]
    const float* __restrict__ conv_w,   // [3][3]
    const float* __restrict__ fc2_w,    // [10][128]
    unsigned short* __restrict__ ws)    // weff4 [25][4][128][8] ++ fc2wb [1280]
{
    int idx = blockIdx.x * 256 + threadIdx.x;   // o*800 + p
    if (idx >= 128 * 800) return;
    if (idx < 1280) ws[102400 + idx] = f2bf(fc2_w[idx]);
    int o = idx / 800, p = idx - o * 800;
    float s = 0.f;
    if (p < 784) {
        int y = p / 28, xx = p - y * 28;
        #pragma unroll
        for (int dr = 0; dr < 3; ++dr) {
            int r = y - dr;
            if (r < 0 || r > 25) continue;
            #pragma unroll
            for (int dc = 0; dc < 3; ++dc) {
                int c = xx - dc;
                if (c < 0 || c > 25) continue;
                s += fc1_w[o * 676 + r * 26 + c] * conv_w[dr * 3 + dc];
            }
        }
    }
    int kt = p >> 5, kk = p & 31;
    ws[kt * 4096 + (kk >> 3) * 1024 + o * 8 + (kk & 7)] = f2bf(s);
}

// Fused: H = relu(X @ Weff^T + b1); out = H @ fc2^T + b2
// BM=64, 36 KB LDS -> 4 blocks/CU = 32 waves/CU. Round-9 pipeline with
// corrected FIFO discipline: GL_B issued BEFORE LD_A each step, av x4
// register sets, uniform vmcnt(3) at each barrier => B flight 2 steps,
// A flight ~2.5 steps actually preserved across barriers.
__global__ __launch_bounds__(512, 8) void fused_fwd(
    const float* __restrict__ x,              // [B][784]
    const unsigned short* __restrict__ weff4, // [25][4][128][8] bf16 (+fc2wb)
    const float* __restrict__ fc1_b,          // [128]
    const float* __restrict__ fc2_b,          // [10]
    float* __restrict__ out,                  // [B][10]
    int B)
{
    __shared__ __align__(16) char pool[POOLB];   // 36 KB; Hs overlays after

    const int tid  = threadIdx.x;
    const int lane = tid & 63;
    const int wid  = tid >> 6;                // 0..7
    const int wr   = wid >> 1;                // 0..3: 16-row band
    const int wc   = wid & 1;                 // 0..1: 64-col half
    const int r16  = lane & 15;
    const int kc   = lane >> 4;               // 0..3 (8-bf16 k-chunk)
    const int m0   = blockIdx.x * BM;
    const unsigned short* fc2wb = weff4 + 102400;

    // ---- A staging: thread t -> row sr, 4-f32 granule g
    const int sr = tid >> 3;                  // 0..63
    const int g  = tid & 7;
    int grow = m0 + sr; if (grow >= B) grow = B - 1;
    const float* xr = x + (size_t)grow * 784;
    const int awb = (g >> 1) * 1024 + sr * 16 + (g & 1) * 8;   // byte in A buf

    f32x4 av[4];

#define LD_A(s_, kt_) do {                                                    \
        int k_ = (kt_) * 32 + g * 4; if (k_ > 780) k_ = 0;                    \
        av[s_] = *reinterpret_cast<const f32x4*>(xr + k_);                    \
    } while (0)

#define WR_A(s_, bi_) do {                                                    \
        uint2 q_ = pack4(av[s_]);                                             \
        *reinterpret_cast<uint2*>(pool + (bi_) * AB + awb) = q_;              \
    } while (0)

#define GL_B(bi_, kt_) __builtin_amdgcn_global_load_lds(                      \
        (const __attribute__((address_space(1))) void*)                      \
            (weff4 + (size_t)(kt_) * 4096 + tid * 8),                         \
        (__attribute__((address_space(3))) void*)                            \
            (pool + BOFFS + (bi_) * BB + tid * 16), 16, 0, 0)

    // ---- frag read offsets (k-major, conflict-free dense 256B groups)
    const int aoff = kc * 1024 + (wr * 16 + r16) * 16;
    const int boff = BOFFS + kc * 2048 + (wc * 64 + r16) * 16;   // j: +256

    f32x4 acc[4];
    #pragma unroll
    for (int j = 0; j < 4; ++j) acc[j] = (f32x4)(0.f);

    asm volatile("s_waitcnt vmcnt(0)" ::: "memory");   // clean FIFO

    // ---- prologue: FIFO = [B0, B1, A0, A1, A2]; WR_A(0) drains A0 (+B0,B1)
    GL_B(0, 0); GL_B(1, 1);
    LD_A(0, 0); LD_A(1, 1); LD_A(2, 2);
    WR_A(0, 0);

    #pragma unroll
    for (int i = 0; i < NKT; ++i) {
        asm volatile("s_waitcnt vmcnt(3) lgkmcnt(0)" ::: "memory");
        __builtin_amdgcn_s_barrier();
        __builtin_amdgcn_sched_barrier(0);

        const char* pa = pool + (i % 3) * AB;
        const char* pb = pool + (i % 3) * BB;   // + BOFFS via boff
        short8 a0 = *reinterpret_cast<const short8*>(pa + aoff);
        short8 b0 = *reinterpret_cast<const short8*>(pb + boff);
        short8 b1 = *reinterpret_cast<const short8*>(pb + boff + 256);
        short8 b2 = *reinterpret_cast<const short8*>(pb + boff + 512);
        short8 b3 = *reinterpret_cast<const short8*>(pb + boff + 768);

        const int kb = (i + 2 <= 24) ? (i + 2) : 24;
        const int ka = (i + 3 <= 24) ? (i + 3) : 24;
        GL_B((i + 2) % 3, kb);                 // B before A (FIFO order)
        LD_A((i + 3) % 4, ka);
        WR_A((i + 1) % 4, (i + 1) % 3);

        acc[0] = __builtin_amdgcn_mfma_f32_16x16x32_bf16(a0, b0, acc[0], 0, 0, 0);
        acc[1] = __builtin_amdgcn_mfma_f32_16x16x32_bf16(a0, b1, acc[1], 0, 0, 0);
        acc[2] = __builtin_amdgcn_mfma_f32_16x16x32_bf16(a0, b2, acc[2], 0, 0, 0);
        acc[3] = __builtin_amdgcn_mfma_f32_16x16x32_bf16(a0, b3, acc[3], 0, 0, 0);
    }
#undef LD_A
#undef WR_A
#undef GL_B

    // drain dummy tail ops before overlaying the pool
    asm volatile("s_waitcnt vmcnt(0) lgkmcnt(0)" ::: "memory");
    __builtin_amdgcn_s_barrier();
    __builtin_amdgcn_sched_barrier(0);

    // ---- epilogue: bias + ReLU -> Hs (bf16), overlays pool ----
    unsigned short (*Hs)[136] = (unsigned short (*)[136])pool;
    #pragma unroll
    for (int j = 0; j < 4; ++j) {
        int ncol = wc * 64 + j * 16 + r16;
        float bias = fc1_b[ncol];
        #pragma unroll
        for (int r = 0; r < 4; ++r) {
            int mrow = wr * 16 + kc * 4 + r;
            float h = acc[j][r] + bias;
            Hs[mrow][ncol] = f2bf(h > 0.f ? h : 0.f);
        }
    }
    __syncthreads();

    // ---- stage 2: out[64][10] = Hs @ fc2^T + b2 (fc2 bf16 from L1) ----
    #pragma unroll
    for (int it = 0; it < 2; ++it) {
        int idx = it * 512 + tid;              // 0..1023, valid < 640
        if (idx < BM * 10) {
            int row = idx / 10, j = idx - row * 10;
            if ((m0 + row) < B) {
                float sum = fc2_b[j];
                const unsigned short* wrow = fc2wb + j * 128;
                #pragma unroll
                for (int n8 = 0; n8 < 16; ++n8) {
                    short8 h = *reinterpret_cast<const short8*>(&Hs[row][n8 * 8]);
                    short8 w = *reinterpret_cast<const short8*>(wrow + n8 * 8);
                    #pragma unroll
                    for (int k2 = 0; k2 < 8; ++k2)
                        sum += bf2f(((unsigned short*)&h)[k2]) *
                               bf2f(((unsigned short*)&w)[k2]);
                }
                out[(size_t)(m0 + row) * 10 + j] = sum;
            }
        }
    }
}

extern "C" void kernel_launch(void* const* d_in, const int* in_sizes, int n_in,
                              void* d_out, int out_size, void* d_ws, size_t ws_size,
                              hipStream_t stream) {
    const float* x      = (const float*)d_in[0];
    const float* conv_w = (const float*)d_in[1];
    const float* fc1_w  = (const float*)d_in[2];
    const float* fc1_b  = (const float*)d_in[3];
    const float* fc2_w  = (const float*)d_in[4];
    const float* fc2_b  = (const float*)d_in[5];
    float* out = (float*)d_out;
    unsigned short* ws = (unsigned short*)d_ws;   // 103680 bf16 = 207360 B

    int B = in_sizes[0] / 784;

    weff_prep<<<(128 * 800 + 255) / 256, 256, 0, stream>>>(fc1_w, conv_w, fc2_w, ws);

    int nblk = (B + BM - 1) / BM;
    fused_fwd<<<nblk, 512, 0, stream>>>(x, ws, fc1_b, fc2_b, out, B);
}